// Round 1
// baseline (584.199 us; speedup 1.0000x reference)
//
#include <hip/hip_runtime.h>
#include <math.h>

// Problem constants (from reference)
#define B_   1024
#define T_   64
#define F_   18
#define U_   128
#define U3_  384   // 3*U
#define D_   64    // dense units

// One block (128 threads = 2 waves) per batch element.
// Key insight: the state table is indexed (id, b); step t only touches
// table[id_t, b], so per batch element the timesteps split into independent
// chains per id. The output depends only on h_new at t=63, i.e. only on the
// chain of timesteps where id_t == id_{63}. Everything else is dead code.
__global__ __launch_bounds__(128) void feedzai_sync_gru_kernel(
    const float* __restrict__ inputs,      // [B, T, F]
    const float* __restrict__ sync_states, // [NIDS, B, U]
    const float* __restrict__ kernel_,     // [F, 3U]
    const float* __restrict__ rec_kernel,  // [U, 3U]
    const float* __restrict__ bias,        // [3U]
    const float* __restrict__ dense_w,     // [U, 64]
    const float* __restrict__ dense_b,     // [64]
    const float* __restrict__ out_w,       // [64, 1]
    const float* __restrict__ out_b,       // [1]
    float* __restrict__ out)               // [B, 1]
{
    const int b = blockIdx.x;
    const int u = threadIdx.x;   // 0..127, one per hidden unit

    __shared__ float sh[U_];     // current hidden state h
    __shared__ float sx[F_];     // current x_t
    __shared__ int   sid[T_];    // per-timestep ids
    __shared__ int   s_flag;     // "h has any nonzero" flag

    const float* inp_b = inputs + (size_t)b * T_ * F_;

    // Stage all 64 ids in one parallel read (column 0, stride F floats).
    if (u < T_) sid[u] = (int)inp_b[u * F_ + 0];
    __syncthreads();

    const int id_last = sid[T_ - 1];

    // Initial h for this chain = pristine sync_states[id_last, b, :].
    float hu = sync_states[((size_t)id_last * B_ + b) * U_ + u];
    sh[u] = hu;
    __syncthreads();

    for (int t = 0; t < T_; ++t) {
        if (sid[t] != id_last) continue;   // uniform branch per block

        // Stage x_t, reset zero-flag.
        if (u < F_) sx[u] = inp_b[t * F_ + u];
        if (u == 0) s_flag = 0;
        __syncthreads();

        hu = sh[u];
        if (hu != 0.0f) s_flag = 1;        // benign same-value race

        // xz = x_t @ kernel + bias   (thread u owns columns u, U+u, 2U+u)
        float xz_z = bias[u];
        float xz_r = bias[U_ + u];
        float xz_h = bias[2 * U_ + u];
        #pragma unroll
        for (int f = 0; f < F_; ++f) {
            const float xv = sx[f];
            const float* kf = kernel_ + f * U3_;
            xz_z += xv * kf[u];
            xz_r += xv * kf[U_ + u];
            xz_h += xv * kf[2 * U_ + u];
        }
        __syncthreads();                   // s_flag writes visible

        // hz = h @ rec_kernel — exactly zero when h == 0 (common first step).
        float hz_z = 0.0f, hz_r = 0.0f, hz_h = 0.0f;
        if (s_flag) {
            for (int k = 0; k < U_; ++k) {
                const float hv = sh[k];
                const float* rk = rec_kernel + k * U3_;
                hz_z += hv * rk[u];
                hz_r += hv * rk[U_ + u];
                hz_h += hv * rk[2 * U_ + u];
            }
        }

        // GRU cell (keras hard_sigmoid + tanh)
        const float z  = fminf(fmaxf(0.2f * (xz_z + hz_z) + 0.5f, 0.0f), 1.0f);
        const float r  = fminf(fmaxf(0.2f * (xz_r + hz_r) + 0.5f, 0.0f), 1.0f);
        const float hh = tanhf(xz_h + r * hz_h);
        const float hn = z * hu + (1.0f - z) * hh;

        __syncthreads();                   // all sh reads done
        sh[u] = hn;
        __syncthreads();                   // new h visible
    }

    // sh now holds h_new at t=63. Dense(128->64) + relu, then dot with out_w.
    float dv = 0.0f;
    if (u < D_) {
        dv = dense_b[u];
        for (int k = 0; k < U_; ++k)
            dv += sh[k] * dense_w[k * D_ + u];   // coalesced across u
        dv = fmaxf(dv, 0.0f);
        dv *= out_w[u];

        // reduce across wave 0's 64 lanes
        #pragma unroll
        for (int off = 32; off > 0; off >>= 1)
            dv += __shfl_down(dv, off, 64);

        if (u == 0)
            out[b] = 1.0f / (1.0f + expf(-(dv + out_b[0])));
    }
}

extern "C" void kernel_launch(void* const* d_in, const int* in_sizes, int n_in,
                              void* d_out, int out_size, void* d_ws, size_t ws_size,
                              hipStream_t stream) {
    const float* inputs      = (const float*)d_in[0];
    const float* sync_states = (const float*)d_in[1];
    const float* kernel_     = (const float*)d_in[2];
    const float* rec_kernel  = (const float*)d_in[3];
    const float* bias        = (const float*)d_in[4];
    const float* dense_w     = (const float*)d_in[5];
    const float* dense_b     = (const float*)d_in[6];
    const float* out_w       = (const float*)d_in[7];
    const float* out_b       = (const float*)d_in[8];
    float* out = (float*)d_out;

    feedzai_sync_gru_kernel<<<dim3(B_), dim3(128), 0, stream>>>(
        inputs, sync_states, kernel_, rec_kernel, bias,
        dense_w, dense_b, out_w, out_b, out);
}